// Round 6
// baseline (883.603 us; speedup 1.0000x reference)
//
#include <hip/hip_runtime.h>
#include <math.h>

constexpr int SEQL = 128;
constexpr int NH   = 8;
constexpr int EMB  = 256;
constexpr int NB   = 64;
constexpr int CCH  = SEQL * NH;                // 1024
constexpr size_t SZ = (size_t)NB * CCH * EMB;  // 16,777,216 elements per plane

typedef short s16x8 __attribute__((ext_vector_type(8)));
typedef float f32x4 __attribute__((ext_vector_type(4)));
typedef unsigned short u16;

// ---- fp32 -> bf16 hi/lo split (RNE) ----
__device__ __forceinline__ unsigned int bfr(float f) {
    unsigned int u = __float_as_uint(f);
    return (u + 0x7fffu + ((u >> 16) & 1u)) >> 16;
}
__device__ __forceinline__ void split2(float v, u16& h, u16& l) {
    unsigned int hb = bfr(v);
    float fh = __uint_as_float(hb << 16);
    unsigned int lb = bfr(v - fh);
    h = (u16)hb; l = (u16)lb;
}
__device__ __forceinline__ float tob(u16 u) {
    return __uint_as_float((unsigned int)u << 16);
}

// async global->LDS, 16B per lane; LDS dest = wave-uniform base + lane*16
__device__ __forceinline__ void gload16(const u16* g, u16* lds) {
    __builtin_amdgcn_global_load_lds(
        (const __attribute__((address_space(1))) unsigned int*)g,
        (__attribute__((address_space(3))) unsigned int*)lds, 16, 0, 0);
}

// ---------------------------------------------------------------------------
// Weight pre-transpose + split: W[k][n] fp32 -> Wt_hi[n][k], Wt_lo[n][k] bf16.
// ---------------------------------------------------------------------------
__global__ __launch_bounds__(256)
void wtconv(const float* __restrict__ s0, const float* __restrict__ s1,
            const float* __restrict__ s2, const float* __restrict__ s3,
            const float* __restrict__ s4, const float* __restrict__ s5,
            const float* __restrict__ s6, u16* __restrict__ dst)
{
    const int mat = blockIdx.x >> 7;
    const float* s = s0;
    if (mat == 1) s = s1; else if (mat == 2) s = s2; else if (mat == 3) s = s3;
    else if (mat == 4) s = s4; else if (mat == 5) s = s5; else if (mat == 6) s = s6;
    const int o = (blockIdx.x & 127) * 512 + threadIdx.x * 2;
    const int n = o >> 8, k = o & 255;
    float v0 = s[(size_t)k * 256 + n];
    float v1 = s[(size_t)(k + 1) * 256 + n];
    u16 h0, l0, h1, l1;
    split2(v0, h0, l0); split2(v1, h1, l1);
    u16* d = dst + (size_t)mat * 131072;
    *(unsigned int*)(d + (size_t)n * 256 + k)         = (unsigned int)h0 | ((unsigned int)h1 << 16);
    *(unsigned int*)(d + 65536 + (size_t)n * 256 + k) = (unsigned int)l0 | ((unsigned int)l1 << 16);
}

// colsum[n] = sum_k W[k][n] for the two BN-folded matrices
__global__ __launch_bounds__(256)
void colsum_k(const float* __restrict__ Wa, const float* __restrict__ Wb,
              float* __restrict__ ca, float* __restrict__ cb)
{
    const float* W = blockIdx.x ? Wb : Wa;
    float* o = blockIdx.x ? cb : ca;
    float s = 0.f;
    for (int k = 0; k < 256; ++k) s += W[(size_t)k * 256 + threadIdx.x];
    o[threadIdx.x] = s;
}

__global__ __launch_bounds__(256)
void prep_eh(const float* __restrict__ E, u16* __restrict__ eh)
{
    const int i = (blockIdx.x * 256 + threadIdx.x) * 4;
    float4 f = *(const float4*)(E + i);
    unsigned int p0 = bfr(f.x) | (bfr(f.y) << 16);
    unsigned int p1 = bfr(f.z) | (bfr(f.w) << 16);
    ((unsigned int*)eh)[(i >> 1)]     = p0;
    ((unsigned int*)eh)[(i >> 1) + 1] = p1;
}

// ---------------------------------------------------------------------------
// BatchNorm stats from hi/lo planes -> per-channel affine (alpha, beta).
// Block = channel c; threads = e columns (coalesced 512B per row visit).
// ---------------------------------------------------------------------------
__global__ __launch_bounds__(256)
void bn_stats_p(const u16* __restrict__ ph, const u16* __restrict__ pl,
                const float* __restrict__ wgt, const float* __restrict__ bias,
                float* __restrict__ alpha, float* __restrict__ beta)
{
    const int c = blockIdx.x, tid = threadIdx.x;
    float s = 0.f, ss = 0.f;
    const size_t base = (size_t)c * 256 + tid;
    for (int nn = 0; nn < NB; ++nn) {
        const size_t idx = base + (size_t)nn * 262144;   // 1024*256
        float v = tob(ph[idx]) + tob(pl[idx]);
        s += v; ss += v * v;
    }
    #pragma unroll
    for (int o = 32; o > 0; o >>= 1) { s += __shfl_xor(s, o); ss += __shfl_xor(ss, o); }
    __shared__ float rs[4], rq[4];
    const int wv = tid >> 6, lane = tid & 63;
    if (lane == 0) { rs[wv] = s; rq[wv] = ss; }
    __syncthreads();
    if (tid == 0) {
        float S  = rs[0] + rs[1] + rs[2] + rs[3];
        float SS = rq[0] + rq[1] + rq[2] + rq[3];
        const float invN = 1.0f / 16384.0f;
        float mean = S * invN;
        float var  = SS * invN - mean * mean;
        float a = rsqrtf(var + 1e-5f) * wgt[c];
        alpha[c] = a;
        beta[c]  = bias[c] - mean * a;
    }
}

// ---------------------------------------------------------------------------
// bf16x3 MFMA GEMM body. 128x128 tile, 4 waves, BK=32, linear LDS [128][32]u16.
// ASRC=1: A planes via global_load_lds; ASRC=0: fp32 A reg-split staging.
// B always planes via global_load_lds.
// BN:   v = alf[c]*acc + bet[c]*wcol[col] + bias   (fold input BatchNorm)
// RESM: 0 none, 1 += resf (fp32), 2 += alr[c]*(resh+resl) + ber[c]
// OUTM: 0 fp32, 1 hi/lo planes, 2 bf16-hi only
// ---------------------------------------------------------------------------
template<int ASRC, int BN, int ACT, int RESM, int OUTM>
__device__ __forceinline__ void mgemm_body(
    const float* __restrict__ Af,
    const u16* __restrict__ Aph, const u16* __restrict__ Apl,
    const u16* __restrict__ WtHi, const u16* __restrict__ WtLo,
    const float* __restrict__ bias,
    const float* __restrict__ resf,
    const u16* __restrict__ resh, const u16* __restrict__ resl,
    const float* __restrict__ alf, const float* __restrict__ bet,
    const float* __restrict__ wcol,
    const float* __restrict__ alr, const float* __restrict__ ber,
    float* __restrict__ outf, u16* __restrict__ outh, u16* __restrict__ outl)
{
    __shared__ u16 Ahi[128 * 32];
    __shared__ u16 Alo[128 * 32];
    __shared__ u16 Bhi[128 * 32];
    __shared__ u16 Blo[128 * 32];

    const int tid = threadIdx.x;
    const int bid = blockIdx.x;
    const int wg  = (bid & 7) * (gridDim.x >> 3) + (bid >> 3);   // XCD swizzle
    const int m0 = (wg >> 1) * 128;
    const int n0 = (wg & 1) * 128;
    const int w = tid >> 6, lane = tid & 63;
    const int wm = w >> 1, wn = w & 1;
    const int fr = lane & 15, g = lane >> 4, fk = g * 8;

    // gload mapping: issue i covers rows w*32+i*16 .. +15; lane -> (row lane>>2, 16B chunk lane&3)
    const int grow = lane >> 2;
    const int gcol = (lane & 3) * 8;

    f32x4 acc[4][4] = {};

    for (int kt = 0; kt < 8; ++kt) {
        const int k0 = kt * 32;
        __syncthreads();                       // prior readers done before refill
        #pragma unroll
        for (int i = 0; i < 2; ++i) {
            const int r = w * 32 + i * 16;     // wave-uniform LDS row base
            const size_t gb = (size_t)(n0 + r + grow) * 256 + k0 + gcol;
            gload16(WtHi + gb, Bhi + r * 32);
            gload16(WtLo + gb, Blo + r * 32);
        }
        if (ASRC == 1) {
            #pragma unroll
            for (int i = 0; i < 2; ++i) {
                const int r = w * 32 + i * 16;
                const size_t ga = (size_t)(m0 + r + grow) * 256 + k0 + gcol;
                gload16(Aph + ga, Ahi + r * 32);
                gload16(Apl + ga, Alo + r * 32);
            }
        } else {
            const int arow = tid >> 1, ac = (tid & 1) * 16;
            const float* ap = Af + (size_t)(m0 + arow) * 256 + k0 + ac;
            u16 hs[16], ls[16];
            #pragma unroll
            for (int q = 0; q < 4; ++q) {
                float4 f = *(const float4*)(ap + q * 4);
                split2(f.x, hs[q*4+0], ls[q*4+0]);
                split2(f.y, hs[q*4+1], ls[q*4+1]);
                split2(f.z, hs[q*4+2], ls[q*4+2]);
                split2(f.w, hs[q*4+3], ls[q*4+3]);
            }
            *(uint4*)(Ahi + arow * 32 + ac)     = *(uint4*)&hs[0];
            *(uint4*)(Ahi + arow * 32 + ac + 8) = *(uint4*)&hs[8];
            *(uint4*)(Alo + arow * 32 + ac)     = *(uint4*)&ls[0];
            *(uint4*)(Alo + arow * 32 + ac + 8) = *(uint4*)&ls[8];
        }
        __syncthreads();                       // vmcnt(0)+lgkmcnt(0) drain -> LDS ready
        // ---- compute ----
        s16x8 ahf[4], alf_[4];
        #pragma unroll
        for (int mf = 0; mf < 4; ++mf) {
            const int r = wm * 64 + mf * 16 + fr;
            ahf[mf]  = *(const s16x8*)(Ahi + r * 32 + fk);
            alf_[mf] = *(const s16x8*)(Alo + r * 32 + fk);
        }
        #pragma unroll
        for (int nf = 0; nf < 4; ++nf) {
            const int cc = wn * 64 + nf * 16 + fr;
            s16x8 bh = *(const s16x8*)(Bhi + cc * 32 + fk);
            s16x8 bl = *(const s16x8*)(Blo + cc * 32 + fk);
            #pragma unroll
            for (int mf = 0; mf < 4; ++mf) {
                acc[mf][nf] = __builtin_amdgcn_mfma_f32_16x16x32_bf16(ahf[mf],  bh, acc[mf][nf], 0, 0, 0);
                acc[mf][nf] = __builtin_amdgcn_mfma_f32_16x16x32_bf16(ahf[mf],  bl, acc[mf][nf], 0, 0, 0);
                acc[mf][nf] = __builtin_amdgcn_mfma_f32_16x16x32_bf16(alf_[mf], bh, acc[mf][nf], 0, 0, 0);
            }
        }
    }

    // ---- epilogue ----
    #pragma unroll
    for (int nf = 0; nf < 4; ++nf) {
        const int col = n0 + wn * 64 + nf * 16 + fr;
        const float bb = bias[col];
        const float wc = BN ? wcol[col] : 0.f;
        #pragma unroll
        for (int mf = 0; mf < 4; ++mf) {
            #pragma unroll
            for (int r = 0; r < 4; ++r) {
                const int row = m0 + wm * 64 + mf * 16 + g * 4 + r;
                const int c = row & 1023;
                float v = acc[mf][nf][r];
                if (BN) v = alf[c] * v + bet[c] * wc + bb;
                else    v += bb;
                if (RESM == 1) v += resf[(size_t)row * 256 + col];
                if (RESM == 2) {
                    const size_t ri = (size_t)row * 256 + col;
                    float rv = tob(resh[ri]) + tob(resl[ri]);
                    v += alr[c] * rv + ber[c];
                }
                if (ACT) v = v > 0.f ? v : 0.01f * v;
                const size_t idx = (size_t)row * 256 + col;
                if (OUTM == 0) outf[idx] = v;
                else if (OUTM == 1) { u16 hh, ll; split2(v, hh, ll); outh[idx] = hh; outl[idx] = ll; }
                else outh[idx] = (u16)bfr(v);
            }
        }
    }
}

// fp32-A variant (reg-split staging; no wave cap -> compiler free on VGPR)
template<int BN, int ACT, int RESM, int OUTM>
__global__ __launch_bounds__(256)
void mgemm_f(const float* __restrict__ Af,
             const u16* __restrict__ WtHi, const u16* __restrict__ WtLo,
             const float* __restrict__ bias,
             const float* __restrict__ resf,
             const u16* __restrict__ resh, const u16* __restrict__ resl,
             const float* __restrict__ alf, const float* __restrict__ bet,
             const float* __restrict__ wcol,
             const float* __restrict__ alr, const float* __restrict__ ber,
             float* __restrict__ outf, u16* __restrict__ outh, u16* __restrict__ outl)
{
    mgemm_body<0, BN, ACT, RESM, OUTM>(Af, nullptr, nullptr, WtHi, WtLo, bias,
        resf, resh, resl, alf, bet, wcol, alr, ber, outf, outh, outl);
}

// plane-A variant (pure global_load_lds staging; cap VGPR at 128 -> 4 waves/SIMD)
template<int BN, int ACT, int RESM, int OUTM>
__global__ __launch_bounds__(256, 4)
void mgemm_p(const u16* __restrict__ Aph, const u16* __restrict__ Apl,
             const u16* __restrict__ WtHi, const u16* __restrict__ WtLo,
             const float* __restrict__ bias,
             const float* __restrict__ resf,
             const u16* __restrict__ resh, const u16* __restrict__ resl,
             const float* __restrict__ alf, const float* __restrict__ bet,
             const float* __restrict__ wcol,
             const float* __restrict__ alr, const float* __restrict__ ber,
             float* __restrict__ outf, u16* __restrict__ outh, u16* __restrict__ outl)
{
    mgemm_body<1, BN, ACT, RESM, OUTM>(nullptr, Aph, Apl, WtHi, WtLo, bias,
        resf, resh, resl, alf, bet, wcol, alr, ber, outf, outh, outl);
}

// ---------------------------------------------------------------------------
// MFMA attention, plane inputs/outputs. Block = (n, h, 64-q slab), 4 waves.
// ---------------------------------------------------------------------------
__global__ __launch_bounds__(256)
void attn_mfma(const u16* __restrict__ Qh, const u16* __restrict__ Ql,
               const u16* __restrict__ Kh,
               const u16* __restrict__ Vh, const u16* __restrict__ Vl,
               const u16* __restrict__ Eh,
               u16* __restrict__ Zh, u16* __restrict__ Zl)
{
    __shared__ u16 att_h[64 * 136];
    __shared__ u16 att_l[64 * 136];
    __shared__ u16 Vt[128 * 72];         // [e-local 128][l-local 64 + pad]

    const int tid = threadIdx.x;
    const int n  = blockIdx.x >> 4;
    const int h  = (blockIdx.x >> 1) & 7;
    const int q0 = (blockIdx.x & 1) * 64;
    const int w = tid >> 6, lane = tid & 63;
    const int fr = lane & 15, g = lane >> 4;
    const int fk = g * 8;

    const size_t nb = (size_t)n * 1024 + h;
    #define GROW(s) ((nb + (size_t)(s) * 8) * 256)

    const int qa = q0 + 16 * w + fr;

    // ---------------- Phase 1: QK + in-register softmax -> P ----------------
    f32x4 acc[8];
    #pragma unroll
    for (int nf = 0; nf < 8; ++nf) acc[nf] = (f32x4){0.f, 0.f, 0.f, 0.f};

    for (int kt = 0; kt < 8; ++kt) {
        s16x8 ah  = *(const s16x8*)(Qh + GROW(qa) + kt * 32 + fk);
        s16x8 al_ = *(const s16x8*)(Ql + GROW(qa) + kt * 32 + fk);
        #pragma unroll
        for (int nf = 0; nf < 8; ++nf) {
            const int l = nf * 16 + fr;
            s16x8 bh = *(const s16x8*)(Kh + GROW(l) + kt * 32 + fk);
            acc[nf] = __builtin_amdgcn_mfma_f32_16x16x32_bf16(ah,  bh, acc[nf], 0, 0, 0);
            acc[nf] = __builtin_amdgcn_mfma_f32_16x16x32_bf16(al_, bh, acc[nf], 0, 0, 0);
        }
    }

    #pragma unroll
    for (int r = 0; r < 4; ++r) {
        const int q    = q0 + 16 * w + g * 4 + r;
        const int qloc = 16 * w + g * 4 + r;
        float v[8];
        float m = -1e30f;
        #pragma unroll
        for (int nf = 0; nf < 8; ++nf) {
            const int l = nf * 16 + fr;
            v[nf] = (l > q) ? acc[nf][r] * 0.0625f : -1e30f;
            m = fmaxf(m, v[nf]);
        }
        #pragma unroll
        for (int o = 8; o > 0; o >>= 1) m = fmaxf(m, __shfl_xor(m, o));
        float s = 0.f;
        #pragma unroll
        for (int nf = 0; nf < 8; ++nf) { v[nf] = expf(v[nf] - m); s += v[nf]; }
        #pragma unroll
        for (int o = 8; o > 0; o >>= 1) s += __shfl_xor(s, o);
        const float inv = 1.f / s;
        #pragma unroll
        for (int nf = 0; nf < 8; ++nf) {
            u16 hh, ll;
            split2(v[nf] * inv, hh, ll);
            att_h[qloc * 136 + nf * 16 + fr] = hh;
            att_l[qloc * 136 + nf * 16 + fr] = ll;
        }
    }

    // ---------------- Phase 2: QE (V.E^T) + skew -> S ----------------
    #pragma unroll
    for (int nf = 0; nf < 8; ++nf) acc[nf] = (f32x4){0.f, 0.f, 0.f, 0.f};

    for (int kt = 0; kt < 8; ++kt) {
        s16x8 ah  = *(const s16x8*)(Vh + GROW(qa) + kt * 32 + fk);
        s16x8 al_ = *(const s16x8*)(Vl + GROW(qa) + kt * 32 + fk);
        #pragma unroll
        for (int nf = 0; nf < 8; ++nf) {
            const int j = nf * 16 + fr;
            s16x8 bh = *(const s16x8*)(Eh + ((size_t)(h * 128 + j)) * 256 + kt * 32 + fk);
            acc[nf] = __builtin_amdgcn_mfma_f32_16x16x32_bf16(ah,  bh, acc[nf], 0, 0, 0);
            acc[nf] = __builtin_amdgcn_mfma_f32_16x16x32_bf16(al_, bh, acc[nf], 0, 0, 0);
        }
    }

    #pragma unroll
    for (int r = 0; r < 4; ++r) {
        const int q    = q0 + 16 * w + g * 4 + r;
        const int qloc = 16 * w + g * 4 + r;
        #pragma unroll
        for (int nf = 0; nf < 8; ++nf) {
            const int j  = nf * 16 + fr;
            const int lt = j - 127 + q;
            float sv = acc[nf][r];
            if (q == 127) sv += 0.0078125f;
            if (lt >= 0) {
                u16 hh, ll;
                split2(sv, hh, ll);
                att_h[qloc * 136 + lt] = hh;
                att_l[qloc * 136 + lt] = ll;
            }
        }
    }

    // ---------------- Phase 3: Z = att . V (quartered Vt) ----------------
    f32x4 az[16];
    #pragma unroll
    for (int nf = 0; nf < 16; ++nf) az[nf] = (f32x4){0.f, 0.f, 0.f, 0.f};

    const int lrow = tid & 63, ec4 = tid >> 6;
    #pragma unroll
    for (int lh = 0; lh < 2; ++lh) {
        #pragma unroll
        for (int eh = 0; eh < 2; ++eh) {
            __syncthreads();
            {
                const u16* vsrc = Vh + GROW(lh * 64 + lrow) + eh * 128 + ec4 * 32;
                #pragma unroll
                for (int c = 0; c < 4; ++c) {
                    uint4 pk = *(const uint4*)(vsrc + c * 8);
                    const u16* t = (const u16*)&pk;
                    const int e = ec4 * 32 + c * 8;
                    #pragma unroll
                    for (int j = 0; j < 8; ++j) Vt[(e + j) * 72 + lrow] = t[j];
                }
            }
            __syncthreads();
            #pragma unroll
            for (int kt = 0; kt < 2; ++kt) {
                const int lg = lh * 64 + kt * 32 + fk;
                s16x8 ah  = *(const s16x8*)(att_h + (16 * w + fr) * 136 + lg);
                s16x8 al_ = *(const s16x8*)(att_l + (16 * w + fr) * 136 + lg);
                #pragma unroll
                for (int nf = 0; nf < 8; ++nf) {
                    s16x8 bh = *(const s16x8*)(Vt + (nf * 16 + fr) * 72 + kt * 32 + fk);
                    az[eh * 8 + nf] = __builtin_amdgcn_mfma_f32_16x16x32_bf16(ah,  bh, az[eh * 8 + nf], 0, 0, 0);
                    az[eh * 8 + nf] = __builtin_amdgcn_mfma_f32_16x16x32_bf16(al_, bh, az[eh * 8 + nf], 0, 0, 0);
                }
            }
        }
    }

    #pragma unroll
    for (int r = 0; r < 4; ++r) {
        const int q = q0 + 16 * w + g * 4 + r;
        #pragma unroll
        for (int nf = 0; nf < 16; ++nf) {
            u16 hh, ll;
            split2(az[nf][r], hh, ll);
            Zh[GROW(q) + nf * 16 + fr] = hh;
            Zl[GROW(q) + nf * 16 + fr] = ll;
        }
    }
    #undef GROW
}

// ---------------------------------------------------------------------------
extern "C" void kernel_launch(void* const* d_in, const int* in_sizes, int n_in,
                              void* d_out, int out_size, void* d_ws, size_t ws_size,
                              hipStream_t stream)
{
    const float* x  = (const float*)d_in[0];
    const float* ei = (const float*)d_in[1];
    const int L = 1;   // only the last layer affects the output
    const float* Wv  = (const float*)d_in[2]  + (size_t)L*EMB*EMB;
    const float* bv  = (const float*)d_in[3]  + (size_t)L*EMB;
    const float* Wk  = (const float*)d_in[4]  + (size_t)L*EMB*EMB;
    const float* bk  = (const float*)d_in[5]  + (size_t)L*EMB;
    const float* Wq  = (const float*)d_in[6]  + (size_t)L*EMB*EMB;
    const float* bq  = (const float*)d_in[7]  + (size_t)L*EMB;
    const float* Ep  = (const float*)d_in[8]  + (size_t)L*NH*SEQL*EMB;
    const float* Wo  = (const float*)d_in[9]  + (size_t)L*EMB*EMB;
    const float* bo  = (const float*)d_in[10] + (size_t)L*EMB;
    const float* b2w = (const float*)d_in[11] + (size_t)L*CCH;
    const float* b2b = (const float*)d_in[12] + (size_t)L*CCH;
    const float* b3w = (const float*)d_in[13] + (size_t)L*CCH;
    const float* b3b = (const float*)d_in[14] + (size_t)L*CCH;
    const float* fW1 = (const float*)d_in[15] + (size_t)L*EMB*EMB;
    const float* fb1 = (const float*)d_in[16] + (size_t)L*EMB;
    const float* fW2 = (const float*)d_in[17] + (size_t)L*EMB*EMB;
    const float* fb2 = (const float*)d_in[18] + (size_t)L*EMB;
    const float* fcW = (const float*)d_in[19];
    const float* fcb = (const float*)d_in[20];

    // workspace map
    float* W0f  = (float*)d_ws;                    // region 0: 2 planes
    float* W1f  = W0f + SZ;                        // region 1: 2 planes
    float* stat = W1f + SZ;                        // 16384 floats reserved
    u16*   Wt   = (u16*)(stat + 16384);            // 7 x 131072 u16
    u16*   ehb  = Wt + (size_t)7 * 131072;         // 262144 u16

    u16* Vh  = (u16*)W0f;      u16* Vl  = Vh + SZ;     // -> later f1h/f1l
    u16* kh  = (u16*)W1f;
    u16* r2h = (u16*)W1f;      u16* r2l = r2h + SZ;    // also r3 (in-place)
    u16* Qh  = (u16*)d_out;    u16* Ql  = Qh + SZ;     // -> Zh/Zl -> final fp32
    float* OUT = (float*)d_out;

    float* a2 = stat + 4096; float* b2 = stat + 5120;
    float* a3 = stat + 6144; float* b3 = stat + 7168;
    float* cs1 = stat + 8192; float* csf = stat + 8448;

    auto slotH = [&](int m){ return Wt + (size_t)m * 131072; };
    auto slotL = [&](int m){ return Wt + (size_t)m * 131072 + 65536; };

    dim3 blk(256);
    wtconv<<<896, blk, 0, stream>>>(Wv, Wk, Wq, Wo, fW1, fW2, fcW, Wt);
    colsum_k<<<2, blk, 0, stream>>>(fW1, fcW, cs1, csf);
    prep_eh<<<256, blk, 0, stream>>>(Ep, ehb);

    // vals -> V planes
    mgemm_f<0,0,0,1><<<1024, blk, 0, stream>>>(ei, slotH(0), slotL(0), bv,
        nullptr, nullptr, nullptr, nullptr, nullptr, nullptr, nullptr, nullptr,
        nullptr, Vh, Vl);
    // keys -> bf16-hi
    mgemm_f<0,0,0,2><<<1024, blk, 0, stream>>>(ei, slotH(1), slotL(1), bk,
        nullptr, nullptr, nullptr, nullptr, nullptr, nullptr, nullptr, nullptr,
        nullptr, kh, nullptr);
    // qrys -> Q planes (d_out)
    mgemm_f<0,0,0,1><<<1024, blk, 0, stream>>>(x, slotH(2), slotL(2), bq,
        nullptr, nullptr, nullptr, nullptr, nullptr, nullptr, nullptr, nullptr,
        nullptr, Qh, Ql);

    // attention: z planes in-place over Q planes
    attn_mfma<<<1024, blk, 0, stream>>>(Qh, Ql, kh, Vh, Vl, ehb, Qh, Ql);

    // r2 = z@Wo + bo + x -> r2 planes (over kh, dead)
    mgemm_p<0,0,1,1><<<1024, blk, 0, stream>>>(Qh, Ql, slotH(3), slotL(3), bo,
        x, nullptr, nullptr, nullptr, nullptr, nullptr, nullptr, nullptr,
        nullptr, r2h, r2l);
    bn_stats_p<<<1024, blk, 0, stream>>>(r2h, r2l, b2w, b2b, a2, b2);

    // ff1 = leaky(BN2(r2)@fW1 + fb1) -> f1 planes (over V planes, dead)
    mgemm_p<1,1,0,1><<<1024, blk, 0, stream>>>(r2h, r2l, slotH(4), slotL(4), fb1,
        nullptr, nullptr, nullptr, a2, b2, cs1, nullptr, nullptr,
        nullptr, Vh, Vl);

    // r3 = ff1@fW2 + fb2 + BN2(r2) -> in-place over r2 planes
    mgemm_p<0,0,2,1><<<1024, blk, 0, stream>>>(Vh, Vl, slotH(5), slotL(5), fb2,
        nullptr, r2h, r2l, nullptr, nullptr, nullptr, a2, b2,
        nullptr, r2h, r2l);
    bn_stats_p<<<1024, blk, 0, stream>>>(r2h, r2l, b3w, b3b, a3, b3);

    // final = BN3(r3)@fcW + fcb -> fp32 d_out (z planes dead)
    mgemm_p<1,0,0,0><<<1024, blk, 0, stream>>>(r2h, r2l, slotH(6), slotL(6), fcb,
        nullptr, nullptr, nullptr, a3, b3, csf, nullptr, nullptr,
        OUT, nullptr, nullptr);
}

// Round 8
// 745.285 us; speedup vs baseline: 1.1856x; 1.1856x over previous
//
#include <hip/hip_runtime.h>
#include <math.h>

constexpr int SEQL = 128;
constexpr int NH   = 8;
constexpr int EMB  = 256;
constexpr int NB   = 64;
constexpr int CCH  = SEQL * NH;                // 1024
constexpr size_t SZ = (size_t)NB * CCH * EMB;  // 16,777,216 elements per plane

typedef short s16x8 __attribute__((ext_vector_type(8)));
typedef float f32x4 __attribute__((ext_vector_type(4)));
typedef unsigned short u16;

// ---- fp32 -> bf16 hi/lo split (RNE) ----
__device__ __forceinline__ unsigned int bfr(float f) {
    unsigned int u = __float_as_uint(f);
    return (u + 0x7fffu + ((u >> 16) & 1u)) >> 16;
}
__device__ __forceinline__ void split2(float v, u16& h, u16& l) {
    unsigned int hb = bfr(v);
    float fh = __uint_as_float(hb << 16);
    unsigned int lb = bfr(v - fh);
    h = (u16)hb; l = (u16)lb;
}
__device__ __forceinline__ float tob(u16 u) {
    return __uint_as_float((unsigned int)u << 16);
}

// async global->LDS, 16B per lane; LDS dest = wave-uniform base + lane*16
__device__ __forceinline__ void gload16(const u16* g, u16* lds) {
    __builtin_amdgcn_global_load_lds(
        (const __attribute__((address_space(1))) unsigned int*)g,
        (__attribute__((address_space(3))) unsigned int*)lds, 16, 0, 0);
}

// ---------------------------------------------------------------------------
// Weight pre-transpose + split: W[k][n] fp32 -> Wt_hi[n][k], Wt_lo[n][k] bf16.
// ---------------------------------------------------------------------------
__global__ __launch_bounds__(256)
void wtconv(const float* __restrict__ s0, const float* __restrict__ s1,
            const float* __restrict__ s2, const float* __restrict__ s3,
            const float* __restrict__ s4, const float* __restrict__ s5,
            const float* __restrict__ s6, u16* __restrict__ dst)
{
    const int mat = blockIdx.x >> 7;
    const float* s = s0;
    if (mat == 1) s = s1; else if (mat == 2) s = s2; else if (mat == 3) s = s3;
    else if (mat == 4) s = s4; else if (mat == 5) s = s5; else if (mat == 6) s = s6;
    const int o = (blockIdx.x & 127) * 512 + threadIdx.x * 2;
    const int n = o >> 8, k = o & 255;
    float v0 = s[(size_t)k * 256 + n];
    float v1 = s[(size_t)(k + 1) * 256 + n];
    u16 h0, l0, h1, l1;
    split2(v0, h0, l0); split2(v1, h1, l1);
    u16* d = dst + (size_t)mat * 131072;
    *(unsigned int*)(d + (size_t)n * 256 + k)         = (unsigned int)h0 | ((unsigned int)h1 << 16);
    *(unsigned int*)(d + 65536 + (size_t)n * 256 + k) = (unsigned int)l0 | ((unsigned int)l1 << 16);
}

// colsum[n] = sum_k W[k][n] for the two BN-folded matrices
__global__ __launch_bounds__(256)
void colsum_k(const float* __restrict__ Wa, const float* __restrict__ Wb,
              float* __restrict__ ca, float* __restrict__ cb)
{
    const float* W = blockIdx.x ? Wb : Wa;
    float* o = blockIdx.x ? cb : ca;
    float s = 0.f;
    for (int k = 0; k < 256; ++k) s += W[(size_t)k * 256 + threadIdx.x];
    o[threadIdx.x] = s;
}

__global__ __launch_bounds__(256)
void prep_eh(const float* __restrict__ E, u16* __restrict__ eh)
{
    const int i = (blockIdx.x * 256 + threadIdx.x) * 4;
    float4 f = *(const float4*)(E + i);
    unsigned int p0 = bfr(f.x) | (bfr(f.y) << 16);
    unsigned int p1 = bfr(f.z) | (bfr(f.w) << 16);
    ((unsigned int*)eh)[(i >> 1)]     = p0;
    ((unsigned int*)eh)[(i >> 1) + 1] = p1;
}

// ---------------------------------------------------------------------------
// BatchNorm stats from hi/lo planes -> per-channel affine (alpha, beta).
// ---------------------------------------------------------------------------
__global__ __launch_bounds__(256)
void bn_stats_p(const u16* __restrict__ ph, const u16* __restrict__ pl,
                const float* __restrict__ wgt, const float* __restrict__ bias,
                float* __restrict__ alpha, float* __restrict__ beta)
{
    const int c = blockIdx.x, tid = threadIdx.x;
    float s = 0.f, ss = 0.f;
    const size_t base = (size_t)c * 256 + tid;
    for (int nn = 0; nn < NB; ++nn) {
        const size_t idx = base + (size_t)nn * 262144;   // 1024*256
        float v = tob(ph[idx]) + tob(pl[idx]);
        s += v; ss += v * v;
    }
    #pragma unroll
    for (int o = 32; o > 0; o >>= 1) { s += __shfl_xor(s, o); ss += __shfl_xor(ss, o); }
    __shared__ float rs[4], rq[4];
    const int wv = tid >> 6, lane = tid & 63;
    if (lane == 0) { rs[wv] = s; rq[wv] = ss; }
    __syncthreads();
    if (tid == 0) {
        float S  = rs[0] + rs[1] + rs[2] + rs[3];
        float SS = rq[0] + rq[1] + rq[2] + rq[3];
        const float invN = 1.0f / 16384.0f;
        float mean = S * invN;
        float var  = SS * invN - mean * mean;
        float a = rsqrtf(var + 1e-5f) * wgt[c];
        alpha[c] = a;
        beta[c]  = bias[c] - mean * a;
    }
}

// ---------------------------------------------------------------------------
// bf16x3 MFMA GEMM body. 128x128 tile, 4 waves, BK=32, linear LDS [128][32]u16.
// Epilogue: LDS-transposed cooperative write (full-sector coalescing).
// ---------------------------------------------------------------------------
template<int ASRC, int BN, int ACT, int RESM, int OUTM>
__device__ __forceinline__ void mgemm_body(
    const float* __restrict__ Af,
    const u16* __restrict__ Aph, const u16* __restrict__ Apl,
    const u16* __restrict__ WtHi, const u16* __restrict__ WtLo,
    const float* __restrict__ bias,
    const float* __restrict__ resf,
    const u16* __restrict__ resh, const u16* __restrict__ resl,
    const float* __restrict__ alf, const float* __restrict__ bet,
    const float* __restrict__ wcol,
    const float* __restrict__ alr, const float* __restrict__ ber,
    float* __restrict__ outf, u16* __restrict__ outh, u16* __restrict__ outl)
{
    __shared__ __align__(16) u16 smem[4 * 128 * 32];   // 32 KB
    u16* Ahi = smem;
    u16* Alo = smem + 4096;
    u16* Bhi = smem + 8192;
    u16* Blo = smem + 12288;

    const int tid = threadIdx.x;
    const int bid = blockIdx.x;
    const int wg  = (bid & 7) * (gridDim.x >> 3) + (bid >> 3);   // XCD swizzle
    const int m0 = (wg >> 1) * 128;
    const int n0 = (wg & 1) * 128;
    const int w = tid >> 6, lane = tid & 63;
    const int wm = w >> 1, wn = w & 1;
    const int fr = lane & 15, g = lane >> 4, fk = g * 8;

    const int grow = lane >> 2;
    const int gcol = (lane & 3) * 8;

    f32x4 acc[4][4] = {};

    for (int kt = 0; kt < 8; ++kt) {
        const int k0 = kt * 32;
        __syncthreads();
        #pragma unroll
        for (int i = 0; i < 2; ++i) {
            const int r = w * 32 + i * 16;
            const size_t gb = (size_t)(n0 + r + grow) * 256 + k0 + gcol;
            gload16(WtHi + gb, Bhi + r * 32);
            gload16(WtLo + gb, Blo + r * 32);
        }
        if (ASRC == 1) {
            #pragma unroll
            for (int i = 0; i < 2; ++i) {
                const int r = w * 32 + i * 16;
                const size_t ga = (size_t)(m0 + r + grow) * 256 + k0 + gcol;
                gload16(Aph + ga, Ahi + r * 32);
                gload16(Apl + ga, Alo + r * 32);
            }
        } else {
            const int arow = tid >> 1, ac = (tid & 1) * 16;
            const float* ap = Af + (size_t)(m0 + arow) * 256 + k0 + ac;
            u16 hs[16], ls[16];
            #pragma unroll
            for (int q = 0; q < 4; ++q) {
                float4 f = *(const float4*)(ap + q * 4);
                split2(f.x, hs[q*4+0], ls[q*4+0]);
                split2(f.y, hs[q*4+1], ls[q*4+1]);
                split2(f.z, hs[q*4+2], ls[q*4+2]);
                split2(f.w, hs[q*4+3], ls[q*4+3]);
            }
            *(uint4*)(Ahi + arow * 32 + ac)     = *(uint4*)&hs[0];
            *(uint4*)(Ahi + arow * 32 + ac + 8) = *(uint4*)&hs[8];
            *(uint4*)(Alo + arow * 32 + ac)     = *(uint4*)&ls[0];
            *(uint4*)(Alo + arow * 32 + ac + 8) = *(uint4*)&ls[8];
        }
        __syncthreads();
        s16x8 ahf[4], alf_[4];
        #pragma unroll
        for (int mf = 0; mf < 4; ++mf) {
            const int r = wm * 64 + mf * 16 + fr;
            ahf[mf]  = *(const s16x8*)(Ahi + r * 32 + fk);
            alf_[mf] = *(const s16x8*)(Alo + r * 32 + fk);
        }
        #pragma unroll
        for (int nf = 0; nf < 4; ++nf) {
            const int cc = wn * 64 + nf * 16 + fr;
            s16x8 bh = *(const s16x8*)(Bhi + cc * 32 + fk);
            s16x8 bl = *(const s16x8*)(Blo + cc * 32 + fk);
            #pragma unroll
            for (int mf = 0; mf < 4; ++mf) {
                acc[mf][nf] = __builtin_amdgcn_mfma_f32_16x16x32_bf16(ahf[mf],  bh, acc[mf][nf], 0, 0, 0);
                acc[mf][nf] = __builtin_amdgcn_mfma_f32_16x16x32_bf16(ahf[mf],  bl, acc[mf][nf], 0, 0, 0);
                acc[mf][nf] = __builtin_amdgcn_mfma_f32_16x16x32_bf16(alf_[mf], bh, acc[mf][nf], 0, 0, 0);
            }
        }
    }

    // ---- epilogue: acc -> LDS (swizzled fp32 [128][64]) -> cooperative out ----
    float* sepi = (float*)smem;           // 8192 floats
    const int erow = tid >> 1;            // 0..127
    const int eseg = tid & 1;             // 32-col segment within the 64-col half
    const int rowg = m0 + erow;
    const int cch  = rowg & 1023;         // BN channel
    const float aBN = BN ? alf[cch] : 0.f;
    const float bBN = BN ? bet[cch] : 0.f;
    const float aR  = (RESM == 2) ? alr[cch] : 0.f;
    const float bR  = (RESM == 2) ? ber[cch] : 0.f;

    #pragma unroll
    for (int h2 = 0; h2 < 2; ++h2) {
        __syncthreads();
        if (wn == h2) {
            #pragma unroll
            for (int nf = 0; nf < 4; ++nf)
                #pragma unroll
                for (int mf = 0; mf < 4; ++mf)
                    #pragma unroll
                    for (int r = 0; r < 4; ++r) {
                        const int row = wm * 64 + mf * 16 + g * 4 + r;
                        const int cl  = nf * 16 + fr;
                        const int sw  = ((((cl >> 2) ^ (row & 15)) & 15) << 2) | (cl & 3);
                        sepi[row * 64 + sw] = acc[mf][nf][r];
                    }
        }
        __syncthreads();
        const int colg0 = n0 + h2 * 64 + eseg * 32;
        const size_t gidx = (size_t)rowg * 256 + colg0;
        float vv[32];
        #pragma unroll
        for (int j = 0; j < 8; ++j) {
            const int c4 = eseg * 8 + j;
            f32x4 tv = *(const f32x4*)(sepi + erow * 64 + (((c4 ^ (erow & 15)) & 15) << 2));
            vv[j*4+0] = tv[0]; vv[j*4+1] = tv[1]; vv[j*4+2] = tv[2]; vv[j*4+3] = tv[3];
        }
        // bias (+wcol) add
        #pragma unroll
        for (int j = 0; j < 8; ++j) {
            float4 bb = *(const float4*)(bias + colg0 + j * 4);
            if (BN) {
                float4 wc = *(const float4*)(wcol + colg0 + j * 4);
                vv[j*4+0] = aBN * vv[j*4+0] + bBN * wc.x + bb.x;
                vv[j*4+1] = aBN * vv[j*4+1] + bBN * wc.y + bb.y;
                vv[j*4+2] = aBN * vv[j*4+2] + bBN * wc.z + bb.z;
                vv[j*4+3] = aBN * vv[j*4+3] + bBN * wc.w + bb.w;
            } else {
                vv[j*4+0] += bb.x; vv[j*4+1] += bb.y; vv[j*4+2] += bb.z; vv[j*4+3] += bb.w;
            }
        }
        if (RESM == 1) {
            #pragma unroll
            for (int j = 0; j < 8; ++j) {
                float4 rv = *(const float4*)(resf + gidx + j * 4);
                vv[j*4+0] += rv.x; vv[j*4+1] += rv.y; vv[j*4+2] += rv.z; vv[j*4+3] += rv.w;
            }
        }
        if (RESM == 2) {
            #pragma unroll
            for (int j = 0; j < 4; ++j) {
                uint4 rh = *(const uint4*)(resh + gidx + j * 8);
                uint4 rl = *(const uint4*)(resl + gidx + j * 8);
                const u16* th = (const u16*)&rh;
                const u16* tl = (const u16*)&rl;
                #pragma unroll
                for (int e = 0; e < 8; ++e)
                    vv[j*8+e] += aR * (tob(th[e]) + tob(tl[e])) + bR;
            }
        }
        if (ACT) {
            #pragma unroll
            for (int j = 0; j < 32; ++j) vv[j] = vv[j] > 0.f ? vv[j] : 0.01f * vv[j];
        }
        if (OUTM == 0) {
            #pragma unroll
            for (int j = 0; j < 8; ++j) {
                float4 o; o.x = vv[j*4+0]; o.y = vv[j*4+1]; o.z = vv[j*4+2]; o.w = vv[j*4+3];
                *(float4*)(outf + gidx + j * 4) = o;
            }
        } else {
            u16 hs[32], ls[32];
            #pragma unroll
            for (int j = 0; j < 32; ++j) split2(vv[j], hs[j], ls[j]);
            #pragma unroll
            for (int j = 0; j < 4; ++j) {
                *(uint4*)(outh + gidx + j * 8) = *(uint4*)&hs[j*8];
                if (OUTM == 1) *(uint4*)(outl + gidx + j * 8) = *(uint4*)&ls[j*8];
            }
        }
    }
}

// fp32-A variant
template<int BN, int ACT, int RESM, int OUTM>
__global__ __launch_bounds__(256)
void mgemm_f(const float* __restrict__ Af,
             const u16* __restrict__ WtHi, const u16* __restrict__ WtLo,
             const float* __restrict__ bias,
             const float* __restrict__ resf,
             const u16* __restrict__ resh, const u16* __restrict__ resl,
             const float* __restrict__ alf, const float* __restrict__ bet,
             const float* __restrict__ wcol,
             const float* __restrict__ alr, const float* __restrict__ ber,
             float* __restrict__ outf, u16* __restrict__ outh, u16* __restrict__ outl)
{
    mgemm_body<0, BN, ACT, RESM, OUTM>(Af, nullptr, nullptr, WtHi, WtLo, bias,
        resf, resh, resl, alf, bet, wcol, alr, ber, outf, outh, outl);
}

// plane-A variant
template<int BN, int ACT, int RESM, int OUTM>
__global__ __launch_bounds__(256, 4)
void mgemm_p(const u16* __restrict__ Aph, const u16* __restrict__ Apl,
             const u16* __restrict__ WtHi, const u16* __restrict__ WtLo,
             const float* __restrict__ bias,
             const float* __restrict__ resf,
             const u16* __restrict__ resh, const u16* __restrict__ resl,
             const float* __restrict__ alf, const float* __restrict__ bet,
             const float* __restrict__ wcol,
             const float* __restrict__ alr, const float* __restrict__ ber,
             float* __restrict__ outf, u16* __restrict__ outh, u16* __restrict__ outl)
{
    mgemm_body<1, BN, ACT, RESM, OUTM>(nullptr, Aph, Apl, WtHi, WtLo, bias,
        resf, resh, resl, alf, bet, wcol, alr, ber, outf, outh, outl);
}

// ---------------------------------------------------------------------------
// MFMA attention, plane inputs/outputs. Block = (n, h, 64-q slab), 4 waves.
// Z written via LDS-staged cooperative coalesced stores.
// ---------------------------------------------------------------------------
__global__ __launch_bounds__(256)
void attn_mfma(const u16* __restrict__ Qh, const u16* __restrict__ Ql,
               const u16* __restrict__ Kh,
               const u16* __restrict__ Vh, const u16* __restrict__ Vl,
               const u16* __restrict__ Eh,
               u16* __restrict__ Zh, u16* __restrict__ Zl)
{
    __shared__ u16 att_h[64 * 136];
    __shared__ u16 att_l[64 * 136];
    __shared__ u16 Vt[128 * 72];

    const int tid = threadIdx.x;
    const int n  = blockIdx.x >> 4;
    const int h  = (blockIdx.x >> 1) & 7;
    const int q0 = (blockIdx.x & 1) * 64;
    const int w = tid >> 6, lane = tid & 63;
    const int fr = lane & 15, g = lane >> 4;
    const int fk = g * 8;

    const size_t nb = (size_t)n * 1024 + h;
    #define GROW(s) ((nb + (size_t)(s) * 8) * 256)

    const int qa = q0 + 16 * w + fr;

    // ---------------- Phase 1: QK + in-register softmax -> P ----------------
    f32x4 acc[8];
    #pragma unroll
    for (int nf = 0; nf < 8; ++nf) acc[nf] = (f32x4){0.f, 0.f, 0.f, 0.f};

    for (int kt = 0; kt < 8; ++kt) {
        s16x8 ah  = *(const s16x8*)(Qh + GROW(qa) + kt * 32 + fk);
        s16x8 al_ = *(const s16x8*)(Ql + GROW(qa) + kt * 32 + fk);
        #pragma unroll
        for (int nf = 0; nf < 8; ++nf) {
            const int l = nf * 16 + fr;
            s16x8 bh = *(const s16x8*)(Kh + GROW(l) + kt * 32 + fk);
            acc[nf] = __builtin_amdgcn_mfma_f32_16x16x32_bf16(ah,  bh, acc[nf], 0, 0, 0);
            acc[nf] = __builtin_amdgcn_mfma_f32_16x16x32_bf16(al_, bh, acc[nf], 0, 0, 0);
        }
    }

    #pragma unroll
    for (int r = 0; r < 4; ++r) {
        const int q    = q0 + 16 * w + g * 4 + r;
        const int qloc = 16 * w + g * 4 + r;
        float v[8];
        float m = -1e30f;
        #pragma unroll
        for (int nf = 0; nf < 8; ++nf) {
            const int l = nf * 16 + fr;
            v[nf] = (l > q) ? acc[nf][r] * 0.0625f : -1e30f;
            m = fmaxf(m, v[nf]);
        }
        #pragma unroll
        for (int o = 8; o > 0; o >>= 1) m = fmaxf(m, __shfl_xor(m, o));
        float s = 0.f;
        #pragma unroll
        for (int nf = 0; nf < 8; ++nf) { v[nf] = expf(v[nf] - m); s += v[nf]; }
        #pragma unroll
        for (int o = 8; o > 0; o >>= 1) s += __shfl_xor(s, o);
        const float inv = 1.f / s;
        #pragma unroll
        for (int nf = 0; nf < 8; ++nf) {
            u16 hh, ll;
            split2(v[nf] * inv, hh, ll);
            att_h[qloc * 136 + nf * 16 + fr] = hh;
            att_l[qloc * 136 + nf * 16 + fr] = ll;
        }
    }

    // ---------------- Phase 2: QE (V.E^T) + skew -> S ----------------
    #pragma unroll
    for (int nf = 0; nf < 8; ++nf) acc[nf] = (f32x4){0.f, 0.f, 0.f, 0.f};

    for (int kt = 0; kt < 8; ++kt) {
        s16x8 ah  = *(const s16x8*)(Vh + GROW(qa) + kt * 32 + fk);
        s16x8 al_ = *(const s16x8*)(Vl + GROW(qa) + kt * 32 + fk);
        #pragma unroll
        for (int nf = 0; nf < 8; ++nf) {
            const int j = nf * 16 + fr;
            s16x8 bh = *(const s16x8*)(Eh + ((size_t)(h * 128 + j)) * 256 + kt * 32 + fk);
            acc[nf] = __builtin_amdgcn_mfma_f32_16x16x32_bf16(ah,  bh, acc[nf], 0, 0, 0);
            acc[nf] = __builtin_amdgcn_mfma_f32_16x16x32_bf16(al_, bh, acc[nf], 0, 0, 0);
        }
    }

    #pragma unroll
    for (int r = 0; r < 4; ++r) {
        const int q    = q0 + 16 * w + g * 4 + r;
        const int qloc = 16 * w + g * 4 + r;
        #pragma unroll
        for (int nf = 0; nf < 8; ++nf) {
            const int j  = nf * 16 + fr;
            const int lt = j - 127 + q;
            float sv = acc[nf][r];
            if (q == 127) sv += 0.0078125f;
            if (lt >= 0) {
                u16 hh, ll;
                split2(sv, hh, ll);
                att_h[qloc * 136 + lt] = hh;
                att_l[qloc * 136 + lt] = ll;
            }
        }
    }

    // ---------------- Phase 3: Z = att . V (quartered Vt) ----------------
    f32x4 az[16];
    #pragma unroll
    for (int nf = 0; nf < 16; ++nf) az[nf] = (f32x4){0.f, 0.f, 0.f, 0.f};

    const int lrow = tid & 63, ec4 = tid >> 6;
    #pragma unroll
    for (int lh = 0; lh < 2; ++lh) {
        #pragma unroll
        for (int eh = 0; eh < 2; ++eh) {
            __syncthreads();
            {
                const u16* vsrc = Vh + GROW(lh * 64 + lrow) + eh * 128 + ec4 * 32;
                #pragma unroll
                for (int c = 0; c < 4; ++c) {
                    uint4 pk = *(const uint4*)(vsrc + c * 8);
                    const u16* t = (const u16*)&pk;
                    const int e = ec4 * 32 + c * 8;
                    #pragma unroll
                    for (int j = 0; j < 8; ++j) Vt[(e + j) * 72 + lrow] = t[j];
                }
            }
            __syncthreads();
            #pragma unroll
            for (int kt = 0; kt < 2; ++kt) {
                const int lg = lh * 64 + kt * 32 + fk;
                s16x8 ah  = *(const s16x8*)(att_h + (16 * w + fr) * 136 + lg);
                s16x8 al_ = *(const s16x8*)(att_l + (16 * w + fr) * 136 + lg);
                #pragma unroll
                for (int nf = 0; nf < 8; ++nf) {
                    s16x8 bh = *(const s16x8*)(Vt + (nf * 16 + fr) * 72 + kt * 32 + fk);
                    az[eh * 8 + nf] = __builtin_amdgcn_mfma_f32_16x16x32_bf16(ah,  bh, az[eh * 8 + nf], 0, 0, 0);
                    az[eh * 8 + nf] = __builtin_amdgcn_mfma_f32_16x16x32_bf16(al_, bh, az[eh * 8 + nf], 0, 0, 0);
                }
            }
        }
    }

    // ---- Z write: stage into att_h/att_l (stride 136), cooperative stores ----
    const int zrow = tid >> 2;        // 0..63
    const int zseg = tid & 3;         // 0..3 (32-col segments of 128)
    #pragma unroll
    for (int ehh = 0; ehh < 2; ++ehh) {
        __syncthreads();              // prior readers (PV or prev stores) done
        #pragma unroll
        for (int r = 0; r < 4; ++r) {
            const int qloc = 16 * w + g * 4 + r;
            #pragma unroll
            for (int nf = 0; nf < 8; ++nf) {
                u16 hh, ll;
                split2(az[ehh * 8 + nf][r], hh, ll);
                att_h[qloc * 136 + nf * 16 + fr] = hh;
                att_l[qloc * 136 + nf * 16 + fr] = ll;
            }
        }
        __syncthreads();
        const size_t zb = GROW(q0 + zrow) + ehh * 128 + zseg * 32;
        #pragma unroll
        for (int j = 0; j < 4; ++j) {
            uint4 ph = *(const uint4*)(att_h + zrow * 136 + zseg * 32 + j * 8);
            uint4 pl = *(const uint4*)(att_l + zrow * 136 + zseg * 32 + j * 8);
            *(uint4*)(Zh + zb + j * 8) = ph;
            *(uint4*)(Zl + zb + j * 8) = pl;
        }
    }
    #undef GROW
}

// ---------------------------------------------------------------------------
extern "C" void kernel_launch(void* const* d_in, const int* in_sizes, int n_in,
                              void* d_out, int out_size, void* d_ws, size_t ws_size,
                              hipStream_t stream)
{
    const float* x  = (const float*)d_in[0];
    const float* ei = (const float*)d_in[1];
    const int L = 1;   // only the last layer affects the output
    const float* Wv  = (const float*)d_in[2]  + (size_t)L*EMB*EMB;
    const float* bv  = (const float*)d_in[3]  + (size_t)L*EMB;
    const float* Wk  = (const float*)d_in[4]  + (size_t)L*EMB*EMB;
    const float* bk  = (const float*)d_in[5]  + (size_t)L*EMB;
    const float* Wq  = (const float*)d_in[6]  + (size_t)L*EMB*EMB;
    const float* bq  = (const float*)d_in[7]  + (size_t)L*EMB;
    const float* Ep  = (const float*)d_in[8]  + (size_t)L*NH*SEQL*EMB;
    const float* Wo  = (const float*)d_in[9]  + (size_t)L*EMB*EMB;
    const float* bo  = (const float*)d_in[10] + (size_t)L*EMB;
    const float* b2w = (const float*)d_in[11] + (size_t)L*CCH;
    const float* b2b = (const float*)d_in[12] + (size_t)L*CCH;
    const float* b3w = (const float*)d_in[13] + (size_t)L*CCH;
    const float* b3b = (const float*)d_in[14] + (size_t)L*CCH;
    const float* fW1 = (const float*)d_in[15] + (size_t)L*EMB*EMB;
    const float* fb1 = (const float*)d_in[16] + (size_t)L*EMB;
    const float* fW2 = (const float*)d_in[17] + (size_t)L*EMB*EMB;
    const float* fb2 = (const float*)d_in[18] + (size_t)L*EMB;
    const float* fcW = (const float*)d_in[19];
    const float* fcb = (const float*)d_in[20];

    // workspace map
    float* W0f  = (float*)d_ws;                    // region 0: 2 planes
    float* W1f  = W0f + SZ;                        // region 1: 2 planes
    float* stat = W1f + SZ;                        // 16384 floats reserved
    u16*   Wt   = (u16*)(stat + 16384);            // 7 x 131072 u16
    u16*   ehb  = Wt + (size_t)7 * 131072;         // 262144 u16

    u16* Vh  = (u16*)W0f;      u16* Vl  = Vh + SZ;     // -> later f1h/f1l
    u16* kh  = (u16*)W1f;
    u16* r2h = (u16*)W1f;      u16* r2l = r2h + SZ;    // also r3 (in-place)
    u16* Qh  = (u16*)d_out;    u16* Ql  = Qh + SZ;     // -> Zh/Zl -> final fp32
    float* OUT = (float*)d_out;

    float* a2 = stat + 4096; float* b2 = stat + 5120;
    float* a3 = stat + 6144; float* b3 = stat + 7168;
    float* cs1 = stat + 8192; float* csf = stat + 8448;

    auto slotH = [&](int m){ return Wt + (size_t)m * 131072; };
    auto slotL = [&](int m){ return Wt + (size_t)m * 131072 + 65536; };

    dim3 blk(256);
    wtconv<<<896, blk, 0, stream>>>(Wv, Wk, Wq, Wo, fW1, fW2, fcW, Wt);
    colsum_k<<<2, blk, 0, stream>>>(fW1, fcW, cs1, csf);
    prep_eh<<<256, blk, 0, stream>>>(Ep, ehb);

    // vals -> V planes
    mgemm_f<0,0,0,1><<<1024, blk, 0, stream>>>(ei, slotH(0), slotL(0), bv,
        nullptr, nullptr, nullptr, nullptr, nullptr, nullptr, nullptr, nullptr,
        nullptr, Vh, Vl);
    // keys -> bf16-hi
    mgemm_f<0,0,0,2><<<1024, blk, 0, stream>>>(ei, slotH(1), slotL(1), bk,
        nullptr, nullptr, nullptr, nullptr, nullptr, nullptr, nullptr, nullptr,
        nullptr, kh, nullptr);
    // qrys -> Q planes (d_out)
    mgemm_f<0,0,0,1><<<1024, blk, 0, stream>>>(x, slotH(2), slotL(2), bq,
        nullptr, nullptr, nullptr, nullptr, nullptr, nullptr, nullptr, nullptr,
        nullptr, Qh, Ql);

    // attention: z planes in-place over Q planes
    attn_mfma<<<1024, blk, 0, stream>>>(Qh, Ql, kh, Vh, Vl, ehb, Qh, Ql);

    // r2 = z@Wo + bo + x -> r2 planes (over kh, dead)
    mgemm_p<0,0,1,1><<<1024, blk, 0, stream>>>(Qh, Ql, slotH(3), slotL(3), bo,
        x, nullptr, nullptr, nullptr, nullptr, nullptr, nullptr, nullptr,
        nullptr, r2h, r2l);
    bn_stats_p<<<1024, blk, 0, stream>>>(r2h, r2l, b2w, b2b, a2, b2);

    // ff1 = leaky(BN2(r2)@fW1 + fb1) -> f1 planes (over V planes, dead)
    mgemm_p<1,1,0,1><<<1024, blk, 0, stream>>>(r2h, r2l, slotH(4), slotL(4), fb1,
        nullptr, nullptr, nullptr, a2, b2, cs1, nullptr, nullptr,
        nullptr, Vh, Vl);

    // r3 = ff1@fW2 + fb2 + BN2(r2) -> in-place over r2 planes
    mgemm_p<0,0,2,1><<<1024, blk, 0, stream>>>(Vh, Vl, slotH(5), slotL(5), fb2,
        nullptr, r2h, r2l, nullptr, nullptr, nullptr, a2, b2,
        nullptr, r2h, r2l);
    bn_stats_p<<<1024, blk, 0, stream>>>(r2h, r2l, b3w, b3b, a3, b3);

    // final = BN3(r3)@fcW + fcb -> fp32 d_out (z planes dead)
    mgemm_p<1,0,0,0><<<1024, blk, 0, stream>>>(r2h, r2l, slotH(6), slotL(6), fcb,
        nullptr, nullptr, nullptr, a3, b3, csf, nullptr, nullptr,
        OUT, nullptr, nullptr);
}